// Round 1
// baseline (410.472 us; speedup 1.0000x reference)
//
#include <hip/hip_runtime.h>

// ---------------------------------------------------------------------------
// Fused attention block: y = Attn(RoPE(xWq+bq), RoPE(xWk+bk), xWv+bv) Wo + bo
// b=2, r=8 (br=16), S=1024, d_model=768, H=12, D=64. All GEMMs bf16-MFMA
// with fp32 accumulate; softmax fp32.
// ---------------------------------------------------------------------------

#define M_TOT 16384   // b*r*S rows
#define DM    768
#define NH    12
#define HD    64
#define SEQ   1024

typedef __attribute__((ext_vector_type(8))) __bf16 bf16x8;
typedef __attribute__((ext_vector_type(4))) float  f32x4;

static __device__ __forceinline__ unsigned short f2b(float f) {
  unsigned u = __builtin_bit_cast(unsigned, f);
  u += 0x7FFFu + ((u >> 16) & 1u);          // round-to-nearest-even
  return (unsigned short)(u >> 16);
}
static __device__ __forceinline__ float b2f(unsigned short s) {
  unsigned u = ((unsigned)s) << 16;
  return __builtin_bit_cast(float, u);
}

// async global->LDS, 16B per lane; l must be wave-uniform base (HW adds lane*16)
static __device__ __forceinline__ void gl_lds16(const void* g, void* l) {
  __builtin_amdgcn_global_load_lds(
      (const __attribute__((address_space(1))) unsigned*)g,
      (__attribute__((address_space(3))) unsigned*)l, 16, 0, 0);
}

// ---------------- x fp32 -> bf16 ----------------
__global__ void cvt_x(const float* __restrict__ x, unsigned short* __restrict__ xb) {
  const int n4 = M_TOT * DM / 4;
  for (int i = blockIdx.x * blockDim.x + threadIdx.x; i < n4; i += gridDim.x * blockDim.x) {
    float4 v = ((const float4*)x)[i];
    ushort4 o;
    o.x = f2b(v.x); o.y = f2b(v.y); o.z = f2b(v.z); o.w = f2b(v.w);
    ((ushort4*)xb)[i] = o;
  }
}

// ---------------- W[k][n] fp32 -> Wt[n][k] bf16 (tiled transpose) ----------------
__global__ void prep_w(const float* __restrict__ Wq, const float* __restrict__ Wk,
                       const float* __restrict__ Wv, const float* __restrict__ Wo,
                       unsigned short* __restrict__ Wt) {
  __shared__ float T[64][65];
  const int wsel = blockIdx.z;
  const float* W = wsel == 0 ? Wq : wsel == 1 ? Wk : wsel == 2 ? Wv : Wo;
  const int k0 = blockIdx.x * 64, n0 = blockIdx.y * 64;
  const int t = threadIdx.x;
#pragma unroll
  for (int p = 0; p < 16; ++p) {
    int e = p * 256 + t, r = e >> 6, c = e & 63;
    T[r][c] = W[(size_t)(k0 + r) * DM + n0 + c];
  }
  __syncthreads();
  unsigned short* dst = Wt + (size_t)wsel * DM * DM;
#pragma unroll
  for (int p = 0; p < 16; ++p) {
    int e = p * 256 + t, r = e >> 6, c = e & 63;   // r = n-row, c = k-col
    dst[(size_t)(n0 + r) * DM + k0 + c] = f2b(T[c][r]);
  }
}

// ---------------- RoPE tables cos/sin[s][j], j<32 ----------------
__global__ void rope_tab(float* __restrict__ cosT, float* __restrict__ sinT) {
  int i = blockIdx.x * blockDim.x + threadIdx.x;   // 32768
  int s = i >> 5, j = i & 31;
  float inv = powf(10000.0f, -(float)j * (1.0f / 32.0f));
  float ang = (float)s * inv;
  cosT[i] = cosf(ang);
  sinT[i] = sinf(ang);
}

// ---------------- 128x128x(K=768) bf16 GEMM, B^T input, bias epilogue -------
template <bool OUTBF>
static __device__ __forceinline__ void gemm128(const unsigned short* __restrict__ A,
                                               const unsigned short* __restrict__ Bt,
                                               const float* __restrict__ bias,
                                               void* __restrict__ Cout,
                                               int m0, int n0) {
  __shared__ unsigned short As[128 * 64];
  __shared__ unsigned short Bs[128 * 64];
  const int tid = threadIdx.x, lane = tid & 63, w = tid >> 6;
  const int wr = w >> 1, wc = w & 1;
  const int lr = lane & 15, g4 = lane >> 4;

  f32x4 acc[4][4];
#pragma unroll
  for (int i = 0; i < 4; ++i)
#pragma unroll
    for (int j = 0; j < 4; ++j) acc[i][j] = (f32x4){0.f, 0.f, 0.f, 0.f};

  for (int kt = 0; kt < DM / 64; ++kt) {
    const int k0 = kt * 64;
#pragma unroll
    for (int p = 0; p < 4; ++p) {
      int cb = p * 256 + w * 64;      // wave-uniform chunk base
      int c = cb + lane;              // per-lane 16B chunk: row=c>>3, col8=c&7
      gl_lds16(A + (size_t)(m0 + (c >> 3)) * DM + k0 + (c & 7) * 8, (char*)As + cb * 16);
      gl_lds16(Bt + (size_t)(n0 + (c >> 3)) * DM + k0 + (c & 7) * 8, (char*)Bs + cb * 16);
    }
    __syncthreads();
#pragma unroll
    for (int kk = 0; kk < 2; ++kk) {
      const int ko = kk * 32 + g4 * 8;
      bf16x8 a[4], b[4];
#pragma unroll
      for (int i = 0; i < 4; ++i) a[i] = *(const bf16x8*)&As[(wr * 64 + i * 16 + lr) * 64 + ko];
#pragma unroll
      for (int j = 0; j < 4; ++j) b[j] = *(const bf16x8*)&Bs[(wc * 64 + j * 16 + lr) * 64 + ko];
#pragma unroll
      for (int i = 0; i < 4; ++i)
#pragma unroll
        for (int j = 0; j < 4; ++j)
          acc[i][j] = __builtin_amdgcn_mfma_f32_16x16x32_bf16(a[i], b[j], acc[i][j], 0, 0, 0);
    }
    __syncthreads();
  }

#pragma unroll
  for (int j = 0; j < 4; ++j) {
    const int col = n0 + wc * 64 + j * 16 + lr;
    const float bv = bias[col];
#pragma unroll
    for (int i = 0; i < 4; ++i) {
      const int rowb = m0 + wr * 64 + i * 16 + g4 * 4;
#pragma unroll
      for (int r = 0; r < 4; ++r) {
        float v = acc[i][j][r] + bv;
        if constexpr (OUTBF)
          ((unsigned short*)Cout)[(size_t)(rowb + r) * DM + col] = f2b(v);
        else
          ((float*)Cout)[(size_t)(rowb + r) * DM + col] = v;
      }
    }
  }
}

__global__ __launch_bounds__(256) void gemm_qkv(const unsigned short* __restrict__ xb,
                                                const unsigned short* __restrict__ Wt,
                                                const float* __restrict__ bq,
                                                const float* __restrict__ bk,
                                                const float* __restrict__ bv,
                                                unsigned short* __restrict__ qkvb) {
  const int z = blockIdx.z;
  const float* bias = z == 0 ? bq : (z == 1 ? bk : bv);
  gemm128<true>(xb, Wt + (size_t)z * DM * DM, bias, qkvb + (size_t)z * M_TOT * DM,
                blockIdx.x * 128, blockIdx.y * 128);
}

__global__ __launch_bounds__(256) void gemm_o(const unsigned short* __restrict__ attnb,
                                              const unsigned short* __restrict__ WtO,
                                              const float* __restrict__ bo,
                                              float* __restrict__ out) {
  gemm128<false>(attnb, WtO, bo, out, blockIdx.x * 128, blockIdx.y * 128);
}

// ---------------- RoPE + pack to per-head layout [(brh)][s][64] bf16 --------
// z=0: Q (scale 1/8 folded in), z=1: K
__global__ void rope_pack(const unsigned short* __restrict__ qkvb,
                          const float* __restrict__ cosT, const float* __restrict__ sinT,
                          unsigned short* __restrict__ Qh, unsigned short* __restrict__ Kh) {
  const int z = blockIdx.z;
  const int idx = blockIdx.x * 256 + threadIdx.x;  // M_TOT*NH*32 total
  const int j = idx & 31;
  const int rest = idx >> 5;
  const int h = rest % NH;
  const int brs = rest / NH;
  const unsigned short* src = qkvb + (size_t)z * M_TOT * DM + (size_t)brs * DM + h * HD;
  float a = b2f(src[j]), b = b2f(src[j + 32]);
  const int s = brs & (SEQ - 1), br = brs >> 10;
  float cs = cosT[s * 32 + j], sn = sinT[s * 32 + j];
  float sc = z ? 1.0f : 0.125f;
  float oa = (a * cs - b * sn) * sc;
  float ob = (b * cs + a * sn) * sc;
  unsigned short* dst = (z ? Kh : Qh) + ((size_t)(br * NH + h) * SEQ + s) * HD;
  dst[j] = f2b(oa);
  dst[j + 32] = f2b(ob);
}

// ---------------- V pack: [brs][h*64+d] -> Vt[(brh)][d][s] (transposed) -----
__global__ void v_pack(const unsigned short* __restrict__ Vb, unsigned short* __restrict__ Vt) {
  __shared__ unsigned short T[64][65];
  const int st = blockIdx.x;    // 16 s-tiles
  const int brh = blockIdx.y;   // 192
  const int br = brh / NH, h = brh - br * NH;
  const int t = threadIdx.x;
  const unsigned short* src = Vb + ((size_t)br * SEQ + st * 64) * DM + h * HD;
#pragma unroll
  for (int p = 0; p < 16; ++p) {
    int e = p * 256 + t, r = e >> 6, c = e & 63;
    T[r][c] = src[(size_t)r * DM + c];
  }
  __syncthreads();
  unsigned short* dst = Vt + (size_t)brh * HD * SEQ + st * 64;
#pragma unroll
  for (int p = 0; p < 16; ++p) {
    int e = p * 256 + t, d = e >> 6, s = e & 63;
    dst[(size_t)d * SEQ + s] = T[s][d];
  }
}

// ---------------- flash attention: per (head, 64-row q-tile) ----------------
// 4 waves; wave w owns q-rows w*16..w*16+15. KVBLK=64. Online softmax fp32.
__global__ __launch_bounds__(256) void attn_fwd(const unsigned short* __restrict__ Qh,
                                                const unsigned short* __restrict__ Kh,
                                                const unsigned short* __restrict__ Vt,
                                                const int* __restrict__ mask,
                                                unsigned short* __restrict__ attnb) {
  __shared__ unsigned short Ks[64 * 64];  // [key][d]
  __shared__ unsigned short Vs[64 * 64];  // [d][key]  (V^T tile)
  __shared__ unsigned short Qs[64 * 64];  // Q tile; reused as P [qrow][key]
  __shared__ int Ms[SEQ];
  const int qt = blockIdx.x, brh = blockIdx.y;
  const int br = brh / NH, h = brh - br * NH;
  const int tid = threadIdx.x, lane = tid & 63, w = tid >> 6;
  const int lr = lane & 15, g4 = lane >> 4;

  *(int4*)&Ms[tid * 4] = *(const int4*)&mask[(size_t)br * SEQ + tid * 4];

  const unsigned short* Qg = Qh + ((size_t)brh * SEQ + qt * 64) * HD;
#pragma unroll
  for (int p = 0; p < 2; ++p) {
    int cb = p * 256 + w * 64;
    gl_lds16(Qg + (size_t)(cb + lane) * 8, (char*)Qs + cb * 16);
  }
  __syncthreads();
  bf16x8 qa[2];
#pragma unroll
  for (int kk = 0; kk < 2; ++kk)
    qa[kk] = *(const bf16x8*)&Qs[(w * 16 + lr) * 64 + kk * 32 + g4 * 8];
  __syncthreads();   // all waves done reading Qs before it becomes P

  f32x4 o[4];
  float m_r[4], l_r[4];
#pragma unroll
  for (int j = 0; j < 4; ++j) o[j] = (f32x4){0.f, 0.f, 0.f, 0.f};
#pragma unroll
  for (int r = 0; r < 4; ++r) { m_r[r] = -INFINITY; l_r[r] = 0.f; }

  const unsigned short* Kg = Kh + (size_t)brh * SEQ * HD;
  const unsigned short* Vg = Vt + (size_t)brh * HD * SEQ;

  for (int kb = 0; kb < SEQ / 64; ++kb) {
#pragma unroll
    for (int p = 0; p < 2; ++p) {
      int cb = p * 256 + w * 64;
      int c = cb + lane;
      gl_lds16(Kg + (size_t)kb * 64 * HD + (size_t)c * 8, (char*)Ks + cb * 16);
      gl_lds16(Vg + (size_t)(c >> 3) * SEQ + kb * 64 + (c & 7) * 8, (char*)Vs + cb * 16);
    }
    __syncthreads();

    // QK^T: wave's 16 q-rows x 64 keys
    f32x4 s4[4];
#pragma unroll
    for (int j = 0; j < 4; ++j) s4[j] = (f32x4){0.f, 0.f, 0.f, 0.f};
#pragma unroll
    for (int kk = 0; kk < 2; ++kk) {
      const int ko = kk * 32 + g4 * 8;
#pragma unroll
      for (int j = 0; j < 4; ++j) {
        bf16x8 kf = *(const bf16x8*)&Ks[(j * 16 + lr) * 64 + ko];
        s4[j] = __builtin_amdgcn_mfma_f32_16x16x32_bf16(qa[kk], kf, s4[j], 0, 0, 0);
      }
    }

    int live[4];
#pragma unroll
    for (int j = 0; j < 4; ++j) live[j] = Ms[kb * 64 + j * 16 + lr];

    // online softmax, one q-row per (g4,r)
#pragma unroll
    for (int r = 0; r < 4; ++r) {
      float sv[4];
      float mx = -INFINITY;
#pragma unroll
      for (int j = 0; j < 4; ++j) {
        sv[j] = live[j] ? s4[j][r] : -INFINITY;
        mx = fmaxf(mx, sv[j]);
      }
#pragma unroll
      for (int off = 8; off >= 1; off >>= 1) mx = fmaxf(mx, __shfl_xor(mx, off));
      float mnew = fmaxf(m_r[r], mx);
      float sc = (mnew == -INFINITY) ? 1.0f : __expf(m_r[r] - mnew);
      float ps = 0.f;
      unsigned short pb[4];
#pragma unroll
      for (int j = 0; j < 4; ++j) {
        float p = (sv[j] == -INFINITY) ? 0.f : __expf(sv[j] - mnew);
        pb[j] = f2b(p);
        ps += p;
      }
#pragma unroll
      for (int off = 8; off >= 1; off >>= 1) ps += __shfl_xor(ps, off);
      l_r[r] = l_r[r] * sc + ps;
      m_r[r] = mnew;
#pragma unroll
      for (int j = 0; j < 4; ++j) o[j][r] *= sc;
#pragma unroll
      for (int j = 0; j < 4; ++j)
        Qs[(w * 16 + g4 * 4 + r) * 64 + j * 16 + lr] = pb[j];  // P write (own wave rows only)
    }

    // PV: o += P @ V  (A from own P rows, B from V^T tile)
#pragma unroll
    for (int kk = 0; kk < 2; ++kk) {
      const int ko = kk * 32 + g4 * 8;
      bf16x8 pa = *(const bf16x8*)&Qs[(w * 16 + lr) * 64 + ko];
#pragma unroll
      for (int j = 0; j < 4; ++j) {
        bf16x8 vf = *(const bf16x8*)&Vs[(j * 16 + lr) * 64 + ko];
        o[j] = __builtin_amdgcn_mfma_f32_16x16x32_bf16(pa, vf, o[j], 0, 0, 0);
      }
    }
    __syncthreads();   // before next tile's staging overwrites Ks/Vs
  }

  unsigned short* dst =
      attnb + ((size_t)(br * SEQ + qt * 64 + w * 16 + g4 * 4)) * DM + h * HD;
#pragma unroll
  for (int r = 0; r < 4; ++r) {
    float inv = l_r[r] > 0.f ? 1.0f / l_r[r] : 0.f;
#pragma unroll
    for (int j = 0; j < 4; ++j)
      dst[(size_t)r * DM + j * 16 + lr] = f2b(o[j][r] * inv);
  }
}

// ---------------------------------------------------------------------------
extern "C" void kernel_launch(void* const* d_in, const int* in_sizes, int n_in,
                              void* d_out, int out_size, void* d_ws, size_t ws_size,
                              hipStream_t stream) {
  const float* x  = (const float*)d_in[0];
  const float* Wq = (const float*)d_in[1];
  const float* bq = (const float*)d_in[2];
  const float* Wk = (const float*)d_in[3];
  const float* bk = (const float*)d_in[4];
  const float* Wv = (const float*)d_in[5];
  const float* bv = (const float*)d_in[6];
  const float* Wo = (const float*)d_in[7];
  const float* bo = (const float*)d_in[8];
  const int* mask = (const int*)d_in[9];
  float* out = (float*)d_out;

  // workspace layout (bytes)
  const size_t OFF_XB   = 0;                       // 25165824 : x bf16
  const size_t OFF_WT   = 25165824;                // 4718592  : Wt[4][n][k] bf16
  const size_t OFF_COS  = 29884416;                // 131072
  const size_t OFF_SIN  = 30015488;                // 131072
  const size_t OFF_QKVB = 30146560;                // 75497472 : q,k,v bf16 [3][M][768]
  const size_t OFF_QH   = 105644032;               // 25165824 : Q head layout
  const size_t OFF_KH   = 130809856;               // 25165824
  const size_t OFF_VT   = 155975680;               // 25165824 : V^T head layout
  const size_t REQUIRED = 181141504;
  if (ws_size < REQUIRED) return;  // ws too small — fail loudly (poisoned out)

  char* w = (char*)d_ws;
  unsigned short* xb   = (unsigned short*)(w + OFF_XB);
  unsigned short* Wt   = (unsigned short*)(w + OFF_WT);
  float* cosT          = (float*)(w + OFF_COS);
  float* sinT          = (float*)(w + OFF_SIN);
  unsigned short* qkvb = (unsigned short*)(w + OFF_QKVB);
  unsigned short* Qh   = (unsigned short*)(w + OFF_QH);
  unsigned short* Kh   = (unsigned short*)(w + OFF_KH);
  unsigned short* Vt   = (unsigned short*)(w + OFF_VT);
  unsigned short* attnb = qkvb;  // alias: qkvb dead after rope_pack/v_pack

  cvt_x<<<2048, 256, 0, stream>>>(x, xb);
  prep_w<<<dim3(12, 12, 4), 256, 0, stream>>>(Wq, Wk, Wv, Wo, Wt);
  rope_tab<<<128, 256, 0, stream>>>(cosT, sinT);
  gemm_qkv<<<dim3(128, 6, 3), 256, 0, stream>>>(xb, Wt, bq, bk, bv, qkvb);
  rope_pack<<<dim3(24576, 1, 2), 256, 0, stream>>>(qkvb, cosT, sinT, Qh, Kh);
  v_pack<<<dim3(16, 192), 256, 0, stream>>>(qkvb + (size_t)2 * M_TOT * DM, Vt);
  attn_fwd<<<dim3(16, 192), 256, 0, stream>>>(Qh, Kh, Vt, mask, attnb);
  gemm_o<<<dim3(128, 6), 256, 0, stream>>>(attnb, Wt + (size_t)3 * DM * DM, bo, out);
}

// Round 2
// 384.409 us; speedup vs baseline: 1.0678x; 1.0678x over previous
//
#include <hip/hip_runtime.h>

// ---------------------------------------------------------------------------
// Fused attention block: y = Attn(RoPE(xWq+bq), RoPE(xWk+bk), xWv+bv) Wo + bo
// b=2, r=8 (br=16), S=1024, d_model=768, H=12, D=64. All GEMMs bf16-MFMA
// with fp32 accumulate; softmax fp32 (log2-domain, native v_exp).
// R2: attn_fwd LDS XOR-swizzle (T2/G4, rule #21: pre-swizzled global src +
//     linear gl_lds dest + swizzled reads), exp2 softmax, defer-max (T13).
// ---------------------------------------------------------------------------

#define M_TOT 16384   // b*r*S rows
#define DM    768
#define NH    12
#define HD    64
#define SEQ   1024

typedef __attribute__((ext_vector_type(8))) __bf16 bf16x8;
typedef __attribute__((ext_vector_type(4))) float  f32x4;

static __device__ __forceinline__ unsigned short f2b(float f) {
  unsigned u = __builtin_bit_cast(unsigned, f);
  u += 0x7FFFu + ((u >> 16) & 1u);          // round-to-nearest-even
  return (unsigned short)(u >> 16);
}
static __device__ __forceinline__ float b2f(unsigned short s) {
  unsigned u = ((unsigned)s) << 16;
  return __builtin_bit_cast(float, u);
}

// async global->LDS, 16B per lane; l must be wave-uniform base (HW adds lane*16)
static __device__ __forceinline__ void gl_lds16(const void* g, void* l) {
  __builtin_amdgcn_global_load_lds(
      (const __attribute__((address_space(1))) unsigned*)g,
      (__attribute__((address_space(3))) unsigned*)l, 16, 0, 0);
}

// XOR swizzle for [64 rows][64 bf16] LDS tiles (row stride 128B = 8 x 16B chunks).
// chunk c = row*8 + col16 ; swizzled col16 ^= (row & 7). Involution.
static __device__ __forceinline__ int swz_src(int c) {      // -> element offset
  return ((c >> 3) << 6) + (((c & 7) ^ ((c >> 3) & 7)) << 3);
}
static __device__ __forceinline__ int swz_rd(int row, int col16) {  // element off
  return (row << 6) + ((col16 ^ (row & 7)) << 3);
}

// ---------------- x fp32 -> bf16 ----------------
__global__ void cvt_x(const float* __restrict__ x, unsigned short* __restrict__ xb) {
  const int n4 = M_TOT * DM / 4;
  for (int i = blockIdx.x * blockDim.x + threadIdx.x; i < n4; i += gridDim.x * blockDim.x) {
    float4 v = ((const float4*)x)[i];
    ushort4 o;
    o.x = f2b(v.x); o.y = f2b(v.y); o.z = f2b(v.z); o.w = f2b(v.w);
    ((ushort4*)xb)[i] = o;
  }
}

// ---------------- W[k][n] fp32 -> Wt[n][k] bf16 (tiled transpose) ----------------
__global__ void prep_w(const float* __restrict__ Wq, const float* __restrict__ Wk,
                       const float* __restrict__ Wv, const float* __restrict__ Wo,
                       unsigned short* __restrict__ Wt) {
  __shared__ float T[64][65];
  const int wsel = blockIdx.z;
  const float* W = wsel == 0 ? Wq : wsel == 1 ? Wk : wsel == 2 ? Wv : Wo;
  const int k0 = blockIdx.x * 64, n0 = blockIdx.y * 64;
  const int t = threadIdx.x;
#pragma unroll
  for (int p = 0; p < 16; ++p) {
    int e = p * 256 + t, r = e >> 6, c = e & 63;
    T[r][c] = W[(size_t)(k0 + r) * DM + n0 + c];
  }
  __syncthreads();
  unsigned short* dst = Wt + (size_t)wsel * DM * DM;
#pragma unroll
  for (int p = 0; p < 16; ++p) {
    int e = p * 256 + t, r = e >> 6, c = e & 63;   // r = n-row, c = k-col
    dst[(size_t)(n0 + r) * DM + k0 + c] = f2b(T[c][r]);
  }
}

// ---------------- RoPE tables cos/sin[s][j], j<32 ----------------
__global__ void rope_tab(float* __restrict__ cosT, float* __restrict__ sinT) {
  int i = blockIdx.x * blockDim.x + threadIdx.x;   // 32768
  int s = i >> 5, j = i & 31;
  float inv = powf(10000.0f, -(float)j * (1.0f / 32.0f));
  float ang = (float)s * inv;
  cosT[i] = cosf(ang);
  sinT[i] = sinf(ang);
}

// ---------------- 128x128x(K=768) bf16 GEMM, B^T input, bias epilogue -------
template <bool OUTBF>
static __device__ __forceinline__ void gemm128(const unsigned short* __restrict__ A,
                                               const unsigned short* __restrict__ Bt,
                                               const float* __restrict__ bias,
                                               void* __restrict__ Cout,
                                               int m0, int n0) {
  __shared__ unsigned short As[128 * 64];
  __shared__ unsigned short Bs[128 * 64];
  const int tid = threadIdx.x, lane = tid & 63, w = tid >> 6;
  const int wr = w >> 1, wc = w & 1;
  const int lr = lane & 15, g4 = lane >> 4;

  f32x4 acc[4][4];
#pragma unroll
  for (int i = 0; i < 4; ++i)
#pragma unroll
    for (int j = 0; j < 4; ++j) acc[i][j] = (f32x4){0.f, 0.f, 0.f, 0.f};

  for (int kt = 0; kt < DM / 64; ++kt) {
    const int k0 = kt * 64;
#pragma unroll
    for (int p = 0; p < 4; ++p) {
      int cb = p * 256 + w * 64;      // wave-uniform chunk base
      int c = cb + lane;              // per-lane 16B chunk: row=c>>3, col8=c&7
      gl_lds16(A + (size_t)(m0 + (c >> 3)) * DM + k0 + (c & 7) * 8, (char*)As + cb * 16);
      gl_lds16(Bt + (size_t)(n0 + (c >> 3)) * DM + k0 + (c & 7) * 8, (char*)Bs + cb * 16);
    }
    __syncthreads();
#pragma unroll
    for (int kk = 0; kk < 2; ++kk) {
      const int ko = kk * 32 + g4 * 8;
      bf16x8 a[4], b[4];
#pragma unroll
      for (int i = 0; i < 4; ++i) a[i] = *(const bf16x8*)&As[(wr * 64 + i * 16 + lr) * 64 + ko];
#pragma unroll
      for (int j = 0; j < 4; ++j) b[j] = *(const bf16x8*)&Bs[(wc * 64 + j * 16 + lr) * 64 + ko];
#pragma unroll
      for (int i = 0; i < 4; ++i)
#pragma unroll
        for (int j = 0; j < 4; ++j)
          acc[i][j] = __builtin_amdgcn_mfma_f32_16x16x32_bf16(a[i], b[j], acc[i][j], 0, 0, 0);
    }
    __syncthreads();
  }

#pragma unroll
  for (int j = 0; j < 4; ++j) {
    const int col = n0 + wc * 64 + j * 16 + lr;
    const float bv = bias[col];
#pragma unroll
    for (int i = 0; i < 4; ++i) {
      const int rowb = m0 + wr * 64 + i * 16 + g4 * 4;
#pragma unroll
      for (int r = 0; r < 4; ++r) {
        float v = acc[i][j][r] + bv;
        if constexpr (OUTBF)
          ((unsigned short*)Cout)[(size_t)(rowb + r) * DM + col] = f2b(v);
        else
          ((float*)Cout)[(size_t)(rowb + r) * DM + col] = v;
      }
    }
  }
}

__global__ __launch_bounds__(256) void gemm_qkv(const unsigned short* __restrict__ xb,
                                                const unsigned short* __restrict__ Wt,
                                                const float* __restrict__ bq,
                                                const float* __restrict__ bk,
                                                const float* __restrict__ bv,
                                                unsigned short* __restrict__ qkvb) {
  const int z = blockIdx.z;
  const float* bias = z == 0 ? bq : (z == 1 ? bk : bv);
  gemm128<true>(xb, Wt + (size_t)z * DM * DM, bias, qkvb + (size_t)z * M_TOT * DM,
                blockIdx.x * 128, blockIdx.y * 128);
}

__global__ __launch_bounds__(256) void gemm_o(const unsigned short* __restrict__ attnb,
                                              const unsigned short* __restrict__ WtO,
                                              const float* __restrict__ bo,
                                              float* __restrict__ out) {
  gemm128<false>(attnb, WtO, bo, out, blockIdx.x * 128, blockIdx.y * 128);
}

// ---------------- RoPE + pack to per-head layout [(brh)][s][64] bf16 --------
// z=0: Q (scale (1/8)*log2(e) folded in -> softmax in log2 domain), z=1: K
__global__ void rope_pack(const unsigned short* __restrict__ qkvb,
                          const float* __restrict__ cosT, const float* __restrict__ sinT,
                          unsigned short* __restrict__ Qh, unsigned short* __restrict__ Kh) {
  const int z = blockIdx.z;
  const int idx = blockIdx.x * 256 + threadIdx.x;  // M_TOT*NH*32 total
  const int j = idx & 31;
  const int rest = idx >> 5;
  const int h = rest % NH;
  const int brs = rest / NH;
  const unsigned short* src = qkvb + (size_t)z * M_TOT * DM + (size_t)brs * DM + h * HD;
  float a = b2f(src[j]), b = b2f(src[j + 32]);
  const int s = brs & (SEQ - 1), br = brs >> 10;
  float cs = cosT[s * 32 + j], sn = sinT[s * 32 + j];
  float sc = z ? 1.0f : 0.125f * 1.44269504f;   // fold 1/sqrt(D) * log2(e) into Q
  float oa = (a * cs - b * sn) * sc;
  float ob = (b * cs + a * sn) * sc;
  unsigned short* dst = (z ? Kh : Qh) + ((size_t)(br * NH + h) * SEQ + s) * HD;
  dst[j] = f2b(oa);
  dst[j + 32] = f2b(ob);
}

// ---------------- V pack: [brs][h*64+d] -> Vt[(brh)][d][s] (transposed) -----
__global__ void v_pack(const unsigned short* __restrict__ Vb, unsigned short* __restrict__ Vt) {
  __shared__ unsigned short T[64][65];
  const int st = blockIdx.x;    // 16 s-tiles
  const int brh = blockIdx.y;   // 192
  const int br = brh / NH, h = brh - br * NH;
  const int t = threadIdx.x;
  const unsigned short* src = Vb + ((size_t)br * SEQ + st * 64) * DM + h * HD;
#pragma unroll
  for (int p = 0; p < 16; ++p) {
    int e = p * 256 + t, r = e >> 6, c = e & 63;
    T[r][c] = src[(size_t)r * DM + c];
  }
  __syncthreads();
  unsigned short* dst = Vt + (size_t)brh * HD * SEQ + st * 64;
#pragma unroll
  for (int p = 0; p < 16; ++p) {
    int e = p * 256 + t, d = e >> 6, s = e & 63;
    dst[(size_t)d * SEQ + s] = T[s][d];
  }
}

// ---------------- flash attention: per (head, 64-row q-tile) ----------------
// 4 waves; wave w owns q-rows w*16..w*16+15. KVBLK=64. Online softmax (log2).
// All [64][64] LDS tiles XOR-swizzled at 16B granularity.
__global__ __launch_bounds__(256) void attn_fwd(const unsigned short* __restrict__ Qh,
                                                const unsigned short* __restrict__ Kh,
                                                const unsigned short* __restrict__ Vt,
                                                const int* __restrict__ mask,
                                                unsigned short* __restrict__ attnb) {
  __shared__ unsigned short Ks[64 * 64];  // [key][d], swizzled
  __shared__ unsigned short Vs[64 * 64];  // [d][key], swizzled
  __shared__ unsigned short Qs[64 * 64];  // Q tile; reused as P [qrow][key], swizzled
  __shared__ int Ms[SEQ];
  const int qt = blockIdx.x, brh = blockIdx.y;
  const int br = brh / NH, h = brh - br * NH;
  const int tid = threadIdx.x, lane = tid & 63, w = tid >> 6;
  const int lr = lane & 15, g4 = lane >> 4;

  *(int4*)&Ms[tid * 4] = *(const int4*)&mask[(size_t)br * SEQ + tid * 4];

  const unsigned short* Qg = Qh + ((size_t)brh * SEQ + qt * 64) * HD;
#pragma unroll
  for (int p = 0; p < 2; ++p) {
    int cb = p * 256 + w * 64;
    gl_lds16(Qg + swz_src(cb + lane), (char*)Qs + cb * 16);
  }
  __syncthreads();
  bf16x8 qa[2];
#pragma unroll
  for (int kk = 0; kk < 2; ++kk)
    qa[kk] = *(const bf16x8*)&Qs[swz_rd(w * 16 + lr, kk * 4 + g4)];
  __syncthreads();   // all waves done reading Qs before it becomes P

  f32x4 o[4];
  float m_r[4], l_r[4];
#pragma unroll
  for (int j = 0; j < 4; ++j) o[j] = (f32x4){0.f, 0.f, 0.f, 0.f};
#pragma unroll
  for (int r = 0; r < 4; ++r) { m_r[r] = -INFINITY; l_r[r] = 0.f; }

  const unsigned short* Kg = Kh + (size_t)brh * SEQ * HD;
  const unsigned short* Vg = Vt + (size_t)brh * HD * SEQ;

  for (int kb = 0; kb < SEQ / 64; ++kb) {
#pragma unroll
    for (int p = 0; p < 2; ++p) {
      int cb = p * 256 + w * 64;
      int c = cb + lane;
      gl_lds16(Kg + (size_t)kb * 64 * HD + swz_src(c), (char*)Ks + cb * 16);
      gl_lds16(Vg + (size_t)(c >> 3) * SEQ + kb * 64 + (((c & 7) ^ ((c >> 3) & 7)) << 3),
               (char*)Vs + cb * 16);
    }
    __syncthreads();

    // QK^T: wave's 16 q-rows x 64 keys (scores already in log2 domain)
    f32x4 s4[4];
#pragma unroll
    for (int j = 0; j < 4; ++j) s4[j] = (f32x4){0.f, 0.f, 0.f, 0.f};
#pragma unroll
    for (int kk = 0; kk < 2; ++kk) {
#pragma unroll
      for (int j = 0; j < 4; ++j) {
        bf16x8 kf = *(const bf16x8*)&Ks[swz_rd(j * 16 + lr, kk * 4 + g4)];
        s4[j] = __builtin_amdgcn_mfma_f32_16x16x32_bf16(qa[kk], kf, s4[j], 0, 0, 0);
      }
    }

    int live[4];
#pragma unroll
    for (int j = 0; j < 4; ++j) live[j] = Ms[kb * 64 + j * 16 + lr];

    // online softmax (log2 domain), one q-row per (g4,r); defer-max THR=8
#pragma unroll
    for (int r = 0; r < 4; ++r) {
      float sv[4];
#pragma unroll
      for (int j = 0; j < 4; ++j) sv[j] = live[j] ? s4[j][r] : -INFINITY;
      float mx = fmaxf(fmaxf(sv[0], sv[1]), fmaxf(sv[2], sv[3]));
#pragma unroll
      for (int off = 8; off >= 1; off >>= 1) mx = fmaxf(mx, __shfl_xor(mx, off));
      if (!__all(mx <= m_r[r] + 8.0f)) {   // rescale only on real max growth
        float mnew = fmaxf(m_r[r], mx);
        float sc = exp2f(m_r[r] - mnew);   // m=-inf -> 0
        l_r[r] *= sc;
#pragma unroll
        for (int j = 0; j < 4; ++j) o[j][r] *= sc;
        m_r[r] = mnew;
      }
      const float mv = m_r[r];
      float ps = 0.f;
      unsigned short pb[4];
#pragma unroll
      for (int j = 0; j < 4; ++j) {
        float p = (sv[j] == -INFINITY) ? 0.f : exp2f(sv[j] - mv);  // bounded by 2^8
        pb[j] = f2b(p);
        ps += p;
      }
#pragma unroll
      for (int off = 8; off >= 1; off >>= 1) ps += __shfl_xor(ps, off);
      l_r[r] += ps;
      const int pr = w * 16 + g4 * 4 + r;
#pragma unroll
      for (int j = 0; j < 4; ++j) {
        const int cl = j * 16 + lr;
        Qs[(pr << 6) + ((((cl >> 3) ^ (pr & 7))) << 3) + (cl & 7)] = pb[j];
      }
    }

    // PV: o += P @ V  (A from own P rows, B from V^T tile)
#pragma unroll
    for (int kk = 0; kk < 2; ++kk) {
      bf16x8 pa = *(const bf16x8*)&Qs[swz_rd(w * 16 + lr, kk * 4 + g4)];
#pragma unroll
      for (int j = 0; j < 4; ++j) {
        bf16x8 vf = *(const bf16x8*)&Vs[swz_rd(j * 16 + lr, kk * 4 + g4)];
        o[j] = __builtin_amdgcn_mfma_f32_16x16x32_bf16(pa, vf, o[j], 0, 0, 0);
      }
    }
    __syncthreads();   // before next tile's staging overwrites Ks/Vs
  }

  unsigned short* dst =
      attnb + ((size_t)(br * SEQ + qt * 64 + w * 16 + g4 * 4)) * DM + h * HD;
#pragma unroll
  for (int r = 0; r < 4; ++r) {
    float inv = l_r[r] > 0.f ? 1.0f / l_r[r] : 0.f;
#pragma unroll
    for (int j = 0; j < 4; ++j)
      dst[(size_t)r * DM + j * 16 + lr] = f2b(o[j][r] * inv);
  }
}

// ---------------------------------------------------------------------------
extern "C" void kernel_launch(void* const* d_in, const int* in_sizes, int n_in,
                              void* d_out, int out_size, void* d_ws, size_t ws_size,
                              hipStream_t stream) {
  const float* x  = (const float*)d_in[0];
  const float* Wq = (const float*)d_in[1];
  const float* bq = (const float*)d_in[2];
  const float* Wk = (const float*)d_in[3];
  const float* bk = (const float*)d_in[4];
  const float* Wv = (const float*)d_in[5];
  const float* bv = (const float*)d_in[6];
  const float* Wo = (const float*)d_in[7];
  const float* bo = (const float*)d_in[8];
  const int* mask = (const int*)d_in[9];
  float* out = (float*)d_out;

  // workspace layout (bytes)
  const size_t OFF_XB   = 0;                       // 25165824 : x bf16
  const size_t OFF_WT   = 25165824;                // 4718592  : Wt[4][n][k] bf16
  const size_t OFF_COS  = 29884416;                // 131072
  const size_t OFF_SIN  = 30015488;                // 131072
  const size_t OFF_QKVB = 30146560;                // 75497472 : q,k,v bf16 [3][M][768]
  const size_t OFF_QH   = 105644032;               // 25165824 : Q head layout
  const size_t OFF_KH   = 130809856;               // 25165824
  const size_t OFF_VT   = 155975680;               // 25165824 : V^T head layout
  const size_t REQUIRED = 181141504;
  if (ws_size < REQUIRED) return;  // ws too small — fail loudly (poisoned out)

  char* w = (char*)d_ws;
  unsigned short* xb   = (unsigned short*)(w + OFF_XB);
  unsigned short* Wt   = (unsigned short*)(w + OFF_WT);
  float* cosT          = (float*)(w + OFF_COS);
  float* sinT          = (float*)(w + OFF_SIN);
  unsigned short* qkvb = (unsigned short*)(w + OFF_QKVB);
  unsigned short* Qh   = (unsigned short*)(w + OFF_QH);
  unsigned short* Kh   = (unsigned short*)(w + OFF_KH);
  unsigned short* Vt   = (unsigned short*)(w + OFF_VT);
  unsigned short* attnb = qkvb;  // alias: qkvb dead after rope_pack/v_pack

  cvt_x<<<2048, 256, 0, stream>>>(x, xb);
  prep_w<<<dim3(12, 12, 4), 256, 0, stream>>>(Wq, Wk, Wv, Wo, Wt);
  rope_tab<<<128, 256, 0, stream>>>(cosT, sinT);
  gemm_qkv<<<dim3(128, 6, 3), 256, 0, stream>>>(xb, Wt, bq, bk, bv, qkvb);
  rope_pack<<<dim3(24576, 1, 2), 256, 0, stream>>>(qkvb, cosT, sinT, Qh, Kh);
  v_pack<<<dim3(16, 192), 256, 0, stream>>>(qkvb + (size_t)2 * M_TOT * DM, Vt);
  attn_fwd<<<dim3(16, 192), 256, 0, stream>>>(Qh, Kh, Vt, mask, attnb);
  gemm_o<<<dim3(128, 6), 256, 0, stream>>>(attnb, Wt + (size_t)3 * DM * DM, bo, out);
}

// Round 3
// 323.679 us; speedup vs baseline: 1.2681x; 1.1876x over previous
//
#include <hip/hip_runtime.h>

// ---------------------------------------------------------------------------
// Fused attention block: y = Attn(RoPE(xWq+bq), RoPE(xWk+bk), xWv+bv) Wo + bo
// b=2, r=8 (br=16), S=1024, d_model=768, H=12, D=64. All GEMMs bf16-MFMA
// with fp32 accumulate; softmax fp32 (log2-domain, native v_exp).
// R3: swapped QK^T -> lane-local softmax rows (in-lane max, partial-l),
//     additive mask, cvt_pk + ds_bpermute P distribution (no LDS P),
//     PV as O^T, Q in registers, setprio around MFMA, vectorized rope_pack.
// ---------------------------------------------------------------------------

#define M_TOT 16384   // b*r*S rows
#define DM    768
#define NH    12
#define HD    64
#define SEQ   1024

typedef __attribute__((ext_vector_type(8))) __bf16 bf16x8;
typedef __attribute__((ext_vector_type(4))) float  f32x4;

static __device__ __forceinline__ unsigned short f2b(float f) {
  unsigned u = __builtin_bit_cast(unsigned, f);
  u += 0x7FFFu + ((u >> 16) & 1u);          // round-to-nearest-even
  return (unsigned short)(u >> 16);
}
static __device__ __forceinline__ float b2f(unsigned short s) {
  unsigned u = ((unsigned)s) << 16;
  return __builtin_bit_cast(float, u);
}
static __device__ __forceinline__ unsigned cvt_pk_bf16(float lo, float hi) {
  unsigned d;
  asm("v_cvt_pk_bf16_f32 %0, %1, %2" : "=v"(d) : "v"(lo), "v"(hi));
  return d;
}

// async global->LDS, 16B per lane; l must be wave-uniform base (HW adds lane*16)
static __device__ __forceinline__ void gl_lds16(const void* g, void* l) {
  __builtin_amdgcn_global_load_lds(
      (const __attribute__((address_space(1))) unsigned*)g,
      (__attribute__((address_space(3))) unsigned*)l, 16, 0, 0);
}

// XOR swizzle for [64 rows][64 bf16] LDS tiles (row stride 128B = 8 x 16B chunks).
// chunk c = row*8 + col16 ; swizzled col16 ^= (row & 7). Involution.
static __device__ __forceinline__ int swz_src(int c) {      // -> element offset
  return ((c >> 3) << 6) + (((c & 7) ^ ((c >> 3) & 7)) << 3);
}
static __device__ __forceinline__ int swz_rd(int row, int col16) {  // element off
  return (row << 6) + ((col16 ^ (row & 7)) << 3);
}

// ---------------- x fp32 -> bf16 ----------------
__global__ void cvt_x(const float* __restrict__ x, unsigned short* __restrict__ xb) {
  const int n4 = M_TOT * DM / 4;
  for (int i = blockIdx.x * blockDim.x + threadIdx.x; i < n4; i += gridDim.x * blockDim.x) {
    float4 v = ((const float4*)x)[i];
    ushort4 o;
    o.x = f2b(v.x); o.y = f2b(v.y); o.z = f2b(v.z); o.w = f2b(v.w);
    ((ushort4*)xb)[i] = o;
  }
}

// ---------------- W[k][n] fp32 -> Wt[n][k] bf16 (tiled transpose) ----------------
__global__ void prep_w(const float* __restrict__ Wq, const float* __restrict__ Wk,
                       const float* __restrict__ Wv, const float* __restrict__ Wo,
                       unsigned short* __restrict__ Wt) {
  __shared__ float T[64][65];
  const int wsel = blockIdx.z;
  const float* W = wsel == 0 ? Wq : wsel == 1 ? Wk : wsel == 2 ? Wv : Wo;
  const int k0 = blockIdx.x * 64, n0 = blockIdx.y * 64;
  const int t = threadIdx.x;
#pragma unroll
  for (int p = 0; p < 16; ++p) {
    int e = p * 256 + t, r = e >> 6, c = e & 63;
    T[r][c] = W[(size_t)(k0 + r) * DM + n0 + c];
  }
  __syncthreads();
  unsigned short* dst = Wt + (size_t)wsel * DM * DM;
#pragma unroll
  for (int p = 0; p < 16; ++p) {
    int e = p * 256 + t, r = e >> 6, c = e & 63;   // r = n-row, c = k-col
    dst[(size_t)(n0 + r) * DM + k0 + c] = f2b(T[c][r]);
  }
}

// ---------------- RoPE tables cos/sin[s][j], j<32 ----------------
__global__ void rope_tab(float* __restrict__ cosT, float* __restrict__ sinT) {
  int i = blockIdx.x * blockDim.x + threadIdx.x;   // 32768
  int s = i >> 5, j = i & 31;
  float inv = powf(10000.0f, -(float)j * (1.0f / 32.0f));
  float ang = (float)s * inv;
  cosT[i] = cosf(ang);
  sinT[i] = sinf(ang);
}

// ---------------- 128x128x(K=768) bf16 GEMM, B^T input, bias epilogue -------
template <bool OUTBF>
static __device__ __forceinline__ void gemm128(const unsigned short* __restrict__ A,
                                               const unsigned short* __restrict__ Bt,
                                               const float* __restrict__ bias,
                                               void* __restrict__ Cout,
                                               int m0, int n0) {
  __shared__ unsigned short As[128 * 64];
  __shared__ unsigned short Bs[128 * 64];
  const int tid = threadIdx.x, lane = tid & 63, w = tid >> 6;
  const int wr = w >> 1, wc = w & 1;
  const int lr = lane & 15, g4 = lane >> 4;

  f32x4 acc[4][4];
#pragma unroll
  for (int i = 0; i < 4; ++i)
#pragma unroll
    for (int j = 0; j < 4; ++j) acc[i][j] = (f32x4){0.f, 0.f, 0.f, 0.f};

  for (int kt = 0; kt < DM / 64; ++kt) {
    const int k0 = kt * 64;
#pragma unroll
    for (int p = 0; p < 4; ++p) {
      int cb = p * 256 + w * 64;      // wave-uniform chunk base
      int c = cb + lane;              // per-lane 16B chunk: row=c>>3, col8=c&7
      gl_lds16(A + (size_t)(m0 + (c >> 3)) * DM + k0 + (c & 7) * 8, (char*)As + cb * 16);
      gl_lds16(Bt + (size_t)(n0 + (c >> 3)) * DM + k0 + (c & 7) * 8, (char*)Bs + cb * 16);
    }
    __syncthreads();
#pragma unroll
    for (int kk = 0; kk < 2; ++kk) {
      const int ko = kk * 32 + g4 * 8;
      bf16x8 a[4], b[4];
#pragma unroll
      for (int i = 0; i < 4; ++i) a[i] = *(const bf16x8*)&As[(wr * 64 + i * 16 + lr) * 64 + ko];
#pragma unroll
      for (int j = 0; j < 4; ++j) b[j] = *(const bf16x8*)&Bs[(wc * 64 + j * 16 + lr) * 64 + ko];
#pragma unroll
      for (int i = 0; i < 4; ++i)
#pragma unroll
        for (int j = 0; j < 4; ++j)
          acc[i][j] = __builtin_amdgcn_mfma_f32_16x16x32_bf16(a[i], b[j], acc[i][j], 0, 0, 0);
    }
    __syncthreads();
  }

#pragma unroll
  for (int j = 0; j < 4; ++j) {
    const int col = n0 + wc * 64 + j * 16 + lr;
    const float bv = bias[col];
#pragma unroll
    for (int i = 0; i < 4; ++i) {
      const int rowb = m0 + wr * 64 + i * 16 + g4 * 4;
#pragma unroll
      for (int r = 0; r < 4; ++r) {
        float v = acc[i][j][r] + bv;
        if constexpr (OUTBF)
          ((unsigned short*)Cout)[(size_t)(rowb + r) * DM + col] = f2b(v);
        else
          ((float*)Cout)[(size_t)(rowb + r) * DM + col] = v;
      }
    }
  }
}

__global__ __launch_bounds__(256) void gemm_qkv(const unsigned short* __restrict__ xb,
                                                const unsigned short* __restrict__ Wt,
                                                const float* __restrict__ bq,
                                                const float* __restrict__ bk,
                                                const float* __restrict__ bv,
                                                unsigned short* __restrict__ qkvb) {
  const int z = blockIdx.z;
  const float* bias = z == 0 ? bq : (z == 1 ? bk : bv);
  gemm128<true>(xb, Wt + (size_t)z * DM * DM, bias, qkvb + (size_t)z * M_TOT * DM,
                blockIdx.x * 128, blockIdx.y * 128);
}

__global__ __launch_bounds__(256) void gemm_o(const unsigned short* __restrict__ attnb,
                                              const unsigned short* __restrict__ WtO,
                                              const float* __restrict__ bo,
                                              float* __restrict__ out) {
  gemm128<false>(attnb, WtO, bo, out, blockIdx.x * 128, blockIdx.y * 128);
}

// ---------------- RoPE + pack to per-head layout [(brh)][s][64] bf16 --------
// z=0: Q (scale (1/8)*log2(e) folded in -> softmax in log2 domain), z=1: K
__global__ void rope_pack(const unsigned short* __restrict__ qkvb,
                          const float* __restrict__ cosT, const float* __restrict__ sinT,
                          unsigned short* __restrict__ Qh, unsigned short* __restrict__ Kh) {
  const int z = blockIdx.z;
  const int idx = blockIdx.x * 256 + threadIdx.x;  // M_TOT*NH = 196608
  const int h = idx % NH, brs = idx / NH;
  const unsigned short* src = qkvb + (size_t)z * M_TOT * DM + (size_t)brs * DM + h * HD;
  const int s = brs & (SEQ - 1), br = brs >> 10;
  unsigned short* dst = (z ? Kh : Qh) + ((size_t)(br * NH + h) * SEQ + s) * HD;
  const float sc = z ? 1.0f : 0.125f * 1.44269504f;   // 1/sqrt(D) * log2(e) on Q
  const float* cr = cosT + s * 32;
  const float* sr = sinT + s * 32;
#pragma unroll
  for (int c = 0; c < 8; ++c) {
    ushort4 av = *(const ushort4*)&src[c * 4];
    ushort4 bv = *(const ushort4*)&src[32 + c * 4];
    float4 cv = *(const float4*)&cr[c * 4];
    float4 snv = *(const float4*)&sr[c * 4];
    ushort4 oa, ob;
    float a, b;
    a = b2f(av.x); b = b2f(bv.x);
    oa.x = f2b((a * cv.x - b * snv.x) * sc); ob.x = f2b((b * cv.x + a * snv.x) * sc);
    a = b2f(av.y); b = b2f(bv.y);
    oa.y = f2b((a * cv.y - b * snv.y) * sc); ob.y = f2b((b * cv.y + a * snv.y) * sc);
    a = b2f(av.z); b = b2f(bv.z);
    oa.z = f2b((a * cv.z - b * snv.z) * sc); ob.z = f2b((b * cv.z + a * snv.z) * sc);
    a = b2f(av.w); b = b2f(bv.w);
    oa.w = f2b((a * cv.w - b * snv.w) * sc); ob.w = f2b((b * cv.w + a * snv.w) * sc);
    *(ushort4*)&dst[c * 4] = oa;
    *(ushort4*)&dst[32 + c * 4] = ob;
  }
}

// ---------------- V pack: [brs][h*64+d] -> Vt[(brh)][d][s] (transposed) -----
__global__ void v_pack(const unsigned short* __restrict__ Vb, unsigned short* __restrict__ Vt) {
  __shared__ unsigned short T[64][65];
  const int st = blockIdx.x;    // 16 s-tiles
  const int brh = blockIdx.y;   // 192
  const int br = brh / NH, h = brh - br * NH;
  const int t = threadIdx.x;
  const unsigned short* src = Vb + ((size_t)br * SEQ + st * 64) * DM + h * HD;
#pragma unroll
  for (int p = 0; p < 16; ++p) {
    int e = p * 256 + t, r = e >> 6, c = e & 63;
    T[r][c] = src[(size_t)r * DM + c];
  }
  __syncthreads();
  unsigned short* dst = Vt + (size_t)brh * HD * SEQ + st * 64;
#pragma unroll
  for (int p = 0; p < 16; ++p) {
    int e = p * 256 + t, d = e >> 6, s = e & 63;
    dst[(size_t)d * SEQ + s] = T[s][d];
  }
}

// ---------------- flash attention: per (head, 64-row q-tile) ----------------
// 4 waves; wave w owns q-rows w*16..w*16+15. KVBLK=64.
// Swapped QK^T: lane (lr,g4) holds S[key=j*16+g4*4+r][q=lr] -> in-lane softmax.
// PV as O^T = mfma(V^T, P): o[j][r] = O[q=lr][d=j*16+g4*4+r].
__global__ __launch_bounds__(256) void attn_fwd(const unsigned short* __restrict__ Qh,
                                                const unsigned short* __restrict__ Kh,
                                                const unsigned short* __restrict__ Vt,
                                                const int* __restrict__ mask,
                                                unsigned short* __restrict__ attnb) {
  __shared__ unsigned short Ks[64 * 64];  // [key][d], swizzled
  __shared__ unsigned short Vs[64 * 64];  // [d][key], swizzled
  __shared__ float Msf[SEQ];              // additive mask (0 or -3e38)
  const int qt = blockIdx.x, brh = blockIdx.y;
  const int br = brh / NH, h = brh - br * NH;
  const int tid = threadIdx.x, lane = tid & 63, w = tid >> 6;
  const int lr = lane & 15, g4 = lane >> 4;

  {
    int4 mi = *(const int4*)&mask[(size_t)br * SEQ + tid * 4];
    float4 mf;
    mf.x = mi.x ? 0.f : -3e38f;
    mf.y = mi.y ? 0.f : -3e38f;
    mf.z = mi.z ? 0.f : -3e38f;
    mf.w = mi.w ? 0.f : -3e38f;
    *(float4*)&Msf[tid * 4] = mf;
  }

  // Q straight to registers (B-fragment: lane holds q=lr, d-chunk g4*8)
  const unsigned short* Qg = Qh + ((size_t)brh * SEQ + qt * 64 + w * 16 + lr) * HD;
  bf16x8 qa[2];
  qa[0] = *(const bf16x8*)(Qg + g4 * 8);
  qa[1] = *(const bf16x8*)(Qg + 32 + g4 * 8);

  f32x4 o[4];
#pragma unroll
  for (int j = 0; j < 4; ++j) o[j] = (f32x4){0.f, 0.f, 0.f, 0.f};
  float m = -INFINITY, lp = 0.f;   // state for q=lr (replicated over g4); lp partial

  const unsigned short* Kg = Kh + (size_t)brh * SEQ * HD;
  const unsigned short* Vg = Vt + (size_t)brh * HD * SEQ;

  // bpermute byte-indices: src lane = ((g4&1)*2 + (t>>1))*16 + lr
  const int bidxA = (((g4 & 1) * 2) * 16 + lr) * 4;
  const int bidxB = bidxA + 64;

  for (int kb = 0; kb < SEQ / 64; ++kb) {
#pragma unroll
    for (int p = 0; p < 2; ++p) {
      int cb = p * 256 + w * 64;
      int c = cb + lane;
      gl_lds16(Kg + (size_t)kb * 64 * HD + swz_src(c), (char*)Ks + cb * 16);
      gl_lds16(Vg + (size_t)(c >> 3) * SEQ + kb * 64 + (((c & 7) ^ ((c >> 3) & 7)) << 3),
               (char*)Vs + cb * 16);
    }
    __syncthreads();

    // QK^T swapped: A = K rows, B = Q -> S[key][q]
    f32x4 s4[4];
#pragma unroll
    for (int j = 0; j < 4; ++j) s4[j] = (f32x4){0.f, 0.f, 0.f, 0.f};
    __builtin_amdgcn_s_setprio(1);
#pragma unroll
    for (int kk = 0; kk < 2; ++kk) {
#pragma unroll
      for (int j = 0; j < 4; ++j) {
        bf16x8 kf = *(const bf16x8*)&Ks[swz_rd(j * 16 + lr, kk * 4 + g4)];
        s4[j] = __builtin_amdgcn_mfma_f32_16x16x32_bf16(kf, qa[kk], s4[j], 0, 0, 0);
      }
    }
    __builtin_amdgcn_s_setprio(0);

    // additive mask (broadcast LDS reads: address depends only on g4,j)
    float sv[4][4];
#pragma unroll
    for (int j = 0; j < 4; ++j) {
      float4 mq = *(const float4*)&Msf[kb * 64 + j * 16 + g4 * 4];
      sv[j][0] = s4[j][0] + mq.x;
      sv[j][1] = s4[j][1] + mq.y;
      sv[j][2] = s4[j][2] + mq.z;
      sv[j][3] = s4[j][3] + mq.w;
    }

    // in-lane max over 16 keys + 2-shfl cross-g4 reduce (state q=lr)
    float mx = sv[0][0];
#pragma unroll
    for (int j = 0; j < 4; ++j)
#pragma unroll
      for (int r = 0; r < 4; ++r) mx = fmaxf(mx, sv[j][r]);
    mx = fmaxf(mx, __shfl_xor(mx, 16));
    mx = fmaxf(mx, __shfl_xor(mx, 32));
    if (!__all(mx <= m + 8.0f)) {     // defer-max (T13)
      float mnew = fmaxf(m, mx);
      float sc = exp2f(m - mnew);     // m=-inf -> 0
      lp *= sc;
#pragma unroll
      for (int j = 0; j < 4; ++j)
#pragma unroll
        for (int r = 0; r < 4; ++r) o[j][r] *= sc;
      m = mnew;
    }

    // p = exp2(s-m), partial-l accumulate, pack to bf16 words
    unsigned wrd[4][2];
#pragma unroll
    for (int j = 0; j < 4; ++j) {
      float p0 = exp2f(sv[j][0] - m), p1 = exp2f(sv[j][1] - m);
      float p2 = exp2f(sv[j][2] - m), p3 = exp2f(sv[j][3] - m);
      lp += (p0 + p1) + (p2 + p3);
      wrd[j][0] = cvt_pk_bf16(p0, p1);
      wrd[j][1] = cvt_pk_bf16(p2, p3);
    }

    // gather P-fragment: lane needs keys kk*32+g4*8..+7 for q=lr.
    // word (kk,t) <- w[kk*2 + (g4>>1)][t&1] from lane ((g4&1)*2 + (t>>1))*16+lr
    union { unsigned u[4]; bf16x8 v; } pg[2];
#pragma unroll
    for (int kk = 0; kk < 2; ++kk) {
#pragma unroll
      for (int t = 0; t < 4; ++t) {
        const int bi = (t < 2) ? bidxA : bidxB;
        unsigned lo = (unsigned)__builtin_amdgcn_ds_bpermute(bi, (int)wrd[kk * 2 + 0][t & 1]);
        unsigned hi = (unsigned)__builtin_amdgcn_ds_bpermute(bi, (int)wrd[kk * 2 + 1][t & 1]);
        pg[kk].u[t] = (lane < 32) ? lo : hi;   // g4>>1 == lane>=32
      }
    }

    // PV as O^T: A = V^T rows (d), B = P (q=lr)
    __builtin_amdgcn_s_setprio(1);
#pragma unroll
    for (int kk = 0; kk < 2; ++kk) {
#pragma unroll
      for (int j = 0; j < 4; ++j) {
        bf16x8 vf = *(const bf16x8*)&Vs[swz_rd(j * 16 + lr, kk * 4 + g4)];
        o[j] = __builtin_amdgcn_mfma_f32_16x16x32_bf16(vf, pg[kk].v, o[j], 0, 0, 0);
      }
    }
    __builtin_amdgcn_s_setprio(0);
    __syncthreads();   // before next tile's staging overwrites Ks/Vs
  }

  // final l reduce (was deferred), divide, packed store
  float l = lp + __shfl_xor(lp, 16);
  l += __shfl_xor(l, 32);
  float inv = l > 0.f ? 1.0f / l : 0.f;
  unsigned short* dst =
      attnb + ((size_t)(br * SEQ + qt * 64 + w * 16 + lr)) * DM + h * HD;
#pragma unroll
  for (int j = 0; j < 4; ++j) {
    ushort4 st;
    st.x = f2b(o[j][0] * inv);
    st.y = f2b(o[j][1] * inv);
    st.z = f2b(o[j][2] * inv);
    st.w = f2b(o[j][3] * inv);
    *(ushort4*)&dst[j * 16 + g4 * 4] = st;
  }
}

// ---------------------------------------------------------------------------
extern "C" void kernel_launch(void* const* d_in, const int* in_sizes, int n_in,
                              void* d_out, int out_size, void* d_ws, size_t ws_size,
                              hipStream_t stream) {
  const float* x  = (const float*)d_in[0];
  const float* Wq = (const float*)d_in[1];
  const float* bq = (const float*)d_in[2];
  const float* Wk = (const float*)d_in[3];
  const float* bk = (const float*)d_in[4];
  const float* Wv = (const float*)d_in[5];
  const float* bv = (const float*)d_in[6];
  const float* Wo = (const float*)d_in[7];
  const float* bo = (const float*)d_in[8];
  const int* mask = (const int*)d_in[9];
  float* out = (float*)d_out;

  // workspace layout (bytes)
  const size_t OFF_XB   = 0;                       // 25165824 : x bf16
  const size_t OFF_WT   = 25165824;                // 4718592  : Wt[4][n][k] bf16
  const size_t OFF_COS  = 29884416;                // 131072
  const size_t OFF_SIN  = 30015488;                // 131072
  const size_t OFF_QKVB = 30146560;                // 75497472 : q,k,v bf16 [3][M][768]
  const size_t OFF_QH   = 105644032;               // 25165824 : Q head layout
  const size_t OFF_KH   = 130809856;               // 25165824
  const size_t OFF_VT   = 155975680;               // 25165824 : V^T head layout
  const size_t REQUIRED = 181141504;
  if (ws_size < REQUIRED) return;  // ws too small — fail loudly (poisoned out)

  char* w = (char*)d_ws;
  unsigned short* xb   = (unsigned short*)(w + OFF_XB);
  unsigned short* Wt   = (unsigned short*)(w + OFF_WT);
  float* cosT          = (float*)(w + OFF_COS);
  float* sinT          = (float*)(w + OFF_SIN);
  unsigned short* qkvb = (unsigned short*)(w + OFF_QKVB);
  unsigned short* Qh   = (unsigned short*)(w + OFF_QH);
  unsigned short* Kh   = (unsigned short*)(w + OFF_KH);
  unsigned short* Vt   = (unsigned short*)(w + OFF_VT);
  unsigned short* attnb = qkvb;  // alias: qkvb dead after rope_pack/v_pack

  cvt_x<<<2048, 256, 0, stream>>>(x, xb);
  prep_w<<<dim3(12, 12, 4), 256, 0, stream>>>(Wq, Wk, Wv, Wo, Wt);
  rope_tab<<<128, 256, 0, stream>>>(cosT, sinT);
  gemm_qkv<<<dim3(128, 6, 3), 256, 0, stream>>>(xb, Wt, bq, bk, bv, qkvb);
  rope_pack<<<dim3(768, 1, 2), 256, 0, stream>>>(qkvb, cosT, sinT, Qh, Kh);
  v_pack<<<dim3(16, 192), 256, 0, stream>>>(qkvb + (size_t)2 * M_TOT * DM, Vt);
  attn_fwd<<<dim3(16, 192), 256, 0, stream>>>(Qh, Kh, Vt, mask, attnb);
  gemm_o<<<dim3(128, 6), 256, 0, stream>>>(attnb, Wt + (size_t)3 * DM * DM, bo, out);
}

// Round 4
// 317.868 us; speedup vs baseline: 1.2913x; 1.0183x over previous
//
#include <hip/hip_runtime.h>

// ---------------------------------------------------------------------------
// Fused attention block: y = Attn(RoPE(xWq+bq), RoPE(xWk+bk), xWv+bv) Wo + bo
// b=2, r=8 (br=16), S=1024, d_model=768, H=12, D=64. All GEMMs bf16-MFMA
// with fp32 accumulate; softmax fp32 (log2-domain, native v_exp).
// R4: PV via 16x16x16 MFMA -> softmax C-layout feeds B-fragment directly,
//     ds_bpermute gather deleted (was 16 bpermute + 8 cndmask per iter).
// ---------------------------------------------------------------------------

#define M_TOT 16384   // b*r*S rows
#define DM    768
#define NH    12
#define HD    64
#define SEQ   1024

typedef __attribute__((ext_vector_type(8))) __bf16 bf16x8;
typedef __attribute__((ext_vector_type(4))) __bf16 bf16x4;
typedef __attribute__((ext_vector_type(4))) short s16x4;
typedef __attribute__((ext_vector_type(4))) float  f32x4;

static __device__ __forceinline__ unsigned short f2b(float f) {
  unsigned u = __builtin_bit_cast(unsigned, f);
  u += 0x7FFFu + ((u >> 16) & 1u);          // round-to-nearest-even
  return (unsigned short)(u >> 16);
}
static __device__ __forceinline__ float b2f(unsigned short s) {
  unsigned u = ((unsigned)s) << 16;
  return __builtin_bit_cast(float, u);
}
static __device__ __forceinline__ unsigned cvt_pk_bf16(float lo, float hi) {
  unsigned d;
  asm("v_cvt_pk_bf16_f32 %0, %1, %2" : "=v"(d) : "v"(lo), "v"(hi));
  return d;
}

// 16x16x16 bf16 MFMA (K=16): A,B = 4 bf16 (2 VGPR) per lane, k = 4*(lane/16)+i
static __device__ __forceinline__ f32x4 mfma16(uint2 a, uint2 b, f32x4 c) {
#if __has_builtin(__builtin_amdgcn_mfma_f32_16x16x16_bf16)
  union U { uint2 u; bf16x4 v; } A, B;
  A.u = a; B.u = b;
  return __builtin_amdgcn_mfma_f32_16x16x16_bf16(A.v, B.v, c, 0, 0, 0);
#else
  union U { uint2 u; s16x4 v; } A, B;
  A.u = a; B.u = b;
  return __builtin_amdgcn_mfma_f32_16x16x16bf16_1k(A.v, B.v, c, 0, 0, 0);
#endif
}

// async global->LDS, 16B per lane; l must be wave-uniform base (HW adds lane*16)
static __device__ __forceinline__ void gl_lds16(const void* g, void* l) {
  __builtin_amdgcn_global_load_lds(
      (const __attribute__((address_space(1))) unsigned*)g,
      (__attribute__((address_space(3))) unsigned*)l, 16, 0, 0);
}

// XOR swizzle for [64 rows][64 bf16] LDS tiles (row stride 128B = 8 x 16B chunks).
// chunk c = row*8 + col16 ; swizzled col16 ^= (row & 7). Involution.
static __device__ __forceinline__ int swz_src(int c) {      // -> element offset
  return ((c >> 3) << 6) + (((c & 7) ^ ((c >> 3) & 7)) << 3);
}
static __device__ __forceinline__ int swz_rd(int row, int col16) {  // element off
  return (row << 6) + ((col16 ^ (row & 7)) << 3);
}

// ---------------- x fp32 -> bf16 ----------------
__global__ void cvt_x(const float* __restrict__ x, unsigned short* __restrict__ xb) {
  const int n4 = M_TOT * DM / 4;
  for (int i = blockIdx.x * blockDim.x + threadIdx.x; i < n4; i += gridDim.x * blockDim.x) {
    float4 v = ((const float4*)x)[i];
    ushort4 o;
    o.x = f2b(v.x); o.y = f2b(v.y); o.z = f2b(v.z); o.w = f2b(v.w);
    ((ushort4*)xb)[i] = o;
  }
}

// ---------------- W[k][n] fp32 -> Wt[n][k] bf16 (tiled transpose) ----------------
__global__ void prep_w(const float* __restrict__ Wq, const float* __restrict__ Wk,
                       const float* __restrict__ Wv, const float* __restrict__ Wo,
                       unsigned short* __restrict__ Wt) {
  __shared__ float T[64][65];
  const int wsel = blockIdx.z;
  const float* W = wsel == 0 ? Wq : wsel == 1 ? Wk : wsel == 2 ? Wv : Wo;
  const int k0 = blockIdx.x * 64, n0 = blockIdx.y * 64;
  const int t = threadIdx.x;
#pragma unroll
  for (int p = 0; p < 16; ++p) {
    int e = p * 256 + t, r = e >> 6, c = e & 63;
    T[r][c] = W[(size_t)(k0 + r) * DM + n0 + c];
  }
  __syncthreads();
  unsigned short* dst = Wt + (size_t)wsel * DM * DM;
#pragma unroll
  for (int p = 0; p < 16; ++p) {
    int e = p * 256 + t, r = e >> 6, c = e & 63;   // r = n-row, c = k-col
    dst[(size_t)(n0 + r) * DM + k0 + c] = f2b(T[c][r]);
  }
}

// ---------------- RoPE tables cos/sin[s][j], j<32 ----------------
__global__ void rope_tab(float* __restrict__ cosT, float* __restrict__ sinT) {
  int i = blockIdx.x * blockDim.x + threadIdx.x;   // 32768
  int s = i >> 5, j = i & 31;
  float inv = powf(10000.0f, -(float)j * (1.0f / 32.0f));
  float ang = (float)s * inv;
  cosT[i] = cosf(ang);
  sinT[i] = sinf(ang);
}

// ---------------- 128x128x(K=768) bf16 GEMM, B^T input, bias epilogue -------
template <bool OUTBF>
static __device__ __forceinline__ void gemm128(const unsigned short* __restrict__ A,
                                               const unsigned short* __restrict__ Bt,
                                               const float* __restrict__ bias,
                                               void* __restrict__ Cout,
                                               int m0, int n0) {
  __shared__ unsigned short As[128 * 64];
  __shared__ unsigned short Bs[128 * 64];
  const int tid = threadIdx.x, lane = tid & 63, w = tid >> 6;
  const int wr = w >> 1, wc = w & 1;
  const int lr = lane & 15, g4 = lane >> 4;

  f32x4 acc[4][4];
#pragma unroll
  for (int i = 0; i < 4; ++i)
#pragma unroll
    for (int j = 0; j < 4; ++j) acc[i][j] = (f32x4){0.f, 0.f, 0.f, 0.f};

  for (int kt = 0; kt < DM / 64; ++kt) {
    const int k0 = kt * 64;
#pragma unroll
    for (int p = 0; p < 4; ++p) {
      int cb = p * 256 + w * 64;      // wave-uniform chunk base
      int c = cb + lane;              // per-lane 16B chunk: row=c>>3, col8=c&7
      gl_lds16(A + (size_t)(m0 + (c >> 3)) * DM + k0 + (c & 7) * 8, (char*)As + cb * 16);
      gl_lds16(Bt + (size_t)(n0 + (c >> 3)) * DM + k0 + (c & 7) * 8, (char*)Bs + cb * 16);
    }
    __syncthreads();
#pragma unroll
    for (int kk = 0; kk < 2; ++kk) {
      const int ko = kk * 32 + g4 * 8;
      bf16x8 a[4], b[4];
#pragma unroll
      for (int i = 0; i < 4; ++i) a[i] = *(const bf16x8*)&As[(wr * 64 + i * 16 + lr) * 64 + ko];
#pragma unroll
      for (int j = 0; j < 4; ++j) b[j] = *(const bf16x8*)&Bs[(wc * 64 + j * 16 + lr) * 64 + ko];
#pragma unroll
      for (int i = 0; i < 4; ++i)
#pragma unroll
        for (int j = 0; j < 4; ++j)
          acc[i][j] = __builtin_amdgcn_mfma_f32_16x16x32_bf16(a[i], b[j], acc[i][j], 0, 0, 0);
    }
    __syncthreads();
  }

#pragma unroll
  for (int j = 0; j < 4; ++j) {
    const int col = n0 + wc * 64 + j * 16 + lr;
    const float bv = bias[col];
#pragma unroll
    for (int i = 0; i < 4; ++i) {
      const int rowb = m0 + wr * 64 + i * 16 + g4 * 4;
#pragma unroll
      for (int r = 0; r < 4; ++r) {
        float v = acc[i][j][r] + bv;
        if constexpr (OUTBF)
          ((unsigned short*)Cout)[(size_t)(rowb + r) * DM + col] = f2b(v);
        else
          ((float*)Cout)[(size_t)(rowb + r) * DM + col] = v;
      }
    }
  }
}

__global__ __launch_bounds__(256) void gemm_qkv(const unsigned short* __restrict__ xb,
                                                const unsigned short* __restrict__ Wt,
                                                const float* __restrict__ bq,
                                                const float* __restrict__ bk,
                                                const float* __restrict__ bv,
                                                unsigned short* __restrict__ qkvb) {
  const int z = blockIdx.z;
  const float* bias = z == 0 ? bq : (z == 1 ? bk : bv);
  gemm128<true>(xb, Wt + (size_t)z * DM * DM, bias, qkvb + (size_t)z * M_TOT * DM,
                blockIdx.x * 128, blockIdx.y * 128);
}

__global__ __launch_bounds__(256) void gemm_o(const unsigned short* __restrict__ attnb,
                                              const unsigned short* __restrict__ WtO,
                                              const float* __restrict__ bo,
                                              float* __restrict__ out) {
  gemm128<false>(attnb, WtO, bo, out, blockIdx.x * 128, blockIdx.y * 128);
}

// ---------------- RoPE + pack to per-head layout [(brh)][s][64] bf16 --------
// z=0: Q (scale (1/8)*log2(e) folded in -> softmax in log2 domain), z=1: K
__global__ void rope_pack(const unsigned short* __restrict__ qkvb,
                          const float* __restrict__ cosT, const float* __restrict__ sinT,
                          unsigned short* __restrict__ Qh, unsigned short* __restrict__ Kh) {
  const int z = blockIdx.z;
  const int idx = blockIdx.x * 256 + threadIdx.x;  // M_TOT*NH = 196608
  const int h = idx % NH, brs = idx / NH;
  const unsigned short* src = qkvb + (size_t)z * M_TOT * DM + (size_t)brs * DM + h * HD;
  const int s = brs & (SEQ - 1), br = brs >> 10;
  unsigned short* dst = (z ? Kh : Qh) + ((size_t)(br * NH + h) * SEQ + s) * HD;
  const float sc = z ? 1.0f : 0.125f * 1.44269504f;   // 1/sqrt(D) * log2(e) on Q
  const float* cr = cosT + s * 32;
  const float* sr = sinT + s * 32;
#pragma unroll
  for (int c = 0; c < 8; ++c) {
    ushort4 av = *(const ushort4*)&src[c * 4];
    ushort4 bv = *(const ushort4*)&src[32 + c * 4];
    float4 cv = *(const float4*)&cr[c * 4];
    float4 snv = *(const float4*)&sr[c * 4];
    ushort4 oa, ob;
    float a, b;
    a = b2f(av.x); b = b2f(bv.x);
    oa.x = f2b((a * cv.x - b * snv.x) * sc); ob.x = f2b((b * cv.x + a * snv.x) * sc);
    a = b2f(av.y); b = b2f(bv.y);
    oa.y = f2b((a * cv.y - b * snv.y) * sc); ob.y = f2b((b * cv.y + a * snv.y) * sc);
    a = b2f(av.z); b = b2f(bv.z);
    oa.z = f2b((a * cv.z - b * snv.z) * sc); ob.z = f2b((b * cv.z + a * snv.z) * sc);
    a = b2f(av.w); b = b2f(bv.w);
    oa.w = f2b((a * cv.w - b * snv.w) * sc); ob.w = f2b((b * cv.w + a * snv.w) * sc);
    *(ushort4*)&dst[c * 4] = oa;
    *(ushort4*)&dst[32 + c * 4] = ob;
  }
}

// ---------------- V pack: [brs][h*64+d] -> Vt[(brh)][d][s] (transposed) -----
__global__ void v_pack(const unsigned short* __restrict__ Vb, unsigned short* __restrict__ Vt) {
  __shared__ unsigned short T[64][65];
  const int st = blockIdx.x;    // 16 s-tiles
  const int brh = blockIdx.y;   // 192
  const int br = brh / NH, h = brh - br * NH;
  const int t = threadIdx.x;
  const unsigned short* src = Vb + ((size_t)br * SEQ + st * 64) * DM + h * HD;
#pragma unroll
  for (int p = 0; p < 16; ++p) {
    int e = p * 256 + t, r = e >> 6, c = e & 63;
    T[r][c] = src[(size_t)r * DM + c];
  }
  __syncthreads();
  unsigned short* dst = Vt + (size_t)brh * HD * SEQ + st * 64;
#pragma unroll
  for (int p = 0; p < 16; ++p) {
    int e = p * 256 + t, d = e >> 6, s = e & 63;
    dst[(size_t)d * SEQ + s] = T[s][d];
  }
}

// ---------------- flash attention: per (head, 64-row q-tile) ----------------
// 4 waves; wave w owns q-rows w*16..w*16+15. KVBLK=64.
// Swapped QK^T: lane (lr,g4) holds S[key=16j+4g4+r][q=lr] -> in-lane softmax.
// PV via 16x16x16 MFMA: post-softmax packed words ARE the B-fragment
// (B[k=4g4+i][col=lr]) -> no cross-lane P distribution at all.
// o[jj][p] = O^T[d=16jj+4g4+p][q=lr].
__global__ __launch_bounds__(256) void attn_fwd(const unsigned short* __restrict__ Qh,
                                                const unsigned short* __restrict__ Kh,
                                                const unsigned short* __restrict__ Vt,
                                                const int* __restrict__ mask,
                                                unsigned short* __restrict__ attnb) {
  __shared__ unsigned short Ks[64 * 64];  // [key][d], swizzled
  __shared__ unsigned short Vs[64 * 64];  // [d][key], swizzled
  __shared__ float Msf[SEQ];              // additive mask (0 or -3e38)
  const int qt = blockIdx.x, brh = blockIdx.y;
  const int br = brh / NH, h = brh - br * NH;
  const int tid = threadIdx.x, lane = tid & 63, w = tid >> 6;
  const int lr = lane & 15, g4 = lane >> 4;

  {
    int4 mi = *(const int4*)&mask[(size_t)br * SEQ + tid * 4];
    float4 mf;
    mf.x = mi.x ? 0.f : -3e38f;
    mf.y = mi.y ? 0.f : -3e38f;
    mf.z = mi.z ? 0.f : -3e38f;
    mf.w = mi.w ? 0.f : -3e38f;
    *(float4*)&Msf[tid * 4] = mf;
  }

  // Q straight to registers (B-fragment: lane holds q=lr, d-chunk g4*8)
  const unsigned short* Qg = Qh + ((size_t)brh * SEQ + qt * 64 + w * 16 + lr) * HD;
  bf16x8 qa[2];
  qa[0] = *(const bf16x8*)(Qg + g4 * 8);
  qa[1] = *(const bf16x8*)(Qg + 32 + g4 * 8);

  f32x4 o[4];
#pragma unroll
  for (int j = 0; j < 4; ++j) o[j] = (f32x4){0.f, 0.f, 0.f, 0.f};
  float m = -INFINITY;
  float lpA = 0.f, lpB = 0.f;   // partial l for q=lr (replicated over g4)

  const unsigned short* Kg = Kh + (size_t)brh * SEQ * HD;
  const unsigned short* Vg = Vt + (size_t)brh * HD * SEQ;

  for (int kb = 0; kb < SEQ / 64; ++kb) {
#pragma unroll
    for (int p = 0; p < 2; ++p) {
      int cb = p * 256 + w * 64;
      int c = cb + lane;
      gl_lds16(Kg + (size_t)kb * 64 * HD + swz_src(c), (char*)Ks + cb * 16);
      gl_lds16(Vg + (size_t)(c >> 3) * SEQ + kb * 64 + (((c & 7) ^ ((c >> 3) & 7)) << 3),
               (char*)Vs + cb * 16);
    }
    __syncthreads();

    // QK^T swapped: A = K rows, B = Q -> S[key][q]
    f32x4 s4[4];
#pragma unroll
    for (int j = 0; j < 4; ++j) s4[j] = (f32x4){0.f, 0.f, 0.f, 0.f};
    __builtin_amdgcn_s_setprio(1);
#pragma unroll
    for (int kk = 0; kk < 2; ++kk) {
#pragma unroll
      for (int j = 0; j < 4; ++j) {
        bf16x8 kf = *(const bf16x8*)&Ks[swz_rd(j * 16 + lr, kk * 4 + g4)];
        s4[j] = __builtin_amdgcn_mfma_f32_16x16x32_bf16(kf, qa[kk], s4[j], 0, 0, 0);
      }
    }
    __builtin_amdgcn_s_setprio(0);

    // additive mask (broadcast LDS reads: address depends only on g4,j)
    float sv[4][4];
#pragma unroll
    for (int j = 0; j < 4; ++j) {
      float4 mq = *(const float4*)&Msf[kb * 64 + j * 16 + g4 * 4];
      sv[j][0] = s4[j][0] + mq.x;
      sv[j][1] = s4[j][1] + mq.y;
      sv[j][2] = s4[j][2] + mq.z;
      sv[j][3] = s4[j][3] + mq.w;
    }

    // in-lane max over 16 keys + 2-shfl cross-g4 reduce (state q=lr)
    float mx = sv[0][0];
#pragma unroll
    for (int j = 0; j < 4; ++j)
#pragma unroll
      for (int r = 0; r < 4; ++r) mx = fmaxf(mx, sv[j][r]);
    mx = fmaxf(mx, __shfl_xor(mx, 16));
    mx = fmaxf(mx, __shfl_xor(mx, 32));
    if (!__all(mx <= m + 8.0f)) {     // defer-max (T13)
      float mnew = fmaxf(m, mx);
      float sc = exp2f(m - mnew);     // m=-inf -> 0
      lpA *= sc; lpB *= sc;
#pragma unroll
      for (int j = 0; j < 4; ++j)
#pragma unroll
        for (int r = 0; r < 4; ++r) o[j][r] *= sc;
      m = mnew;
    }

    // p = exp2(s-m); packed words = 16x16x16 B-fragments (k = 4*g4 + i)
    uint2 wb[4];
#pragma unroll
    for (int j = 0; j < 4; ++j) {
      float p0 = exp2f(sv[j][0] - m), p1 = exp2f(sv[j][1] - m);
      float p2 = exp2f(sv[j][2] - m), p3 = exp2f(sv[j][3] - m);
      if (j & 1) lpB += (p0 + p1) + (p2 + p3);
      else       lpA += (p0 + p1) + (p2 + p3);
      wb[j].x = cvt_pk_bf16(p0, p1);
      wb[j].y = cvt_pk_bf16(p2, p3);
    }

    // PV as O^T: o[jj] += sum_j V^T[16jj..][16j..] (A, b64 reads) * P_j (B)
    __builtin_amdgcn_s_setprio(1);
#pragma unroll
    for (int jj = 0; jj < 4; ++jj) {
      const int row = jj * 16 + lr;
#pragma unroll
      for (int j = 0; j < 4; ++j) {
        const int c8 = j * 4 + g4;   // 8B chunk within row
        uint2 av = *(const uint2*)&Vs[(row << 6) + ((((c8 >> 1) ^ (lr & 7))) << 3) +
                                      ((c8 & 1) << 2)];
        o[jj] = mfma16(av, wb[j], o[jj]);
      }
    }
    __builtin_amdgcn_s_setprio(0);
    __syncthreads();   // before next tile's staging overwrites Ks/Vs
  }

  // final l reduce (was deferred), divide, packed store
  float lp = lpA + lpB;
  float l = lp + __shfl_xor(lp, 16);
  l += __shfl_xor(l, 32);
  float inv = l > 0.f ? 1.0f / l : 0.f;
  unsigned short* dst =
      attnb + ((size_t)(br * SEQ + qt * 64 + w * 16 + lr)) * DM + h * HD;
#pragma unroll
  for (int j = 0; j < 4; ++j) {
    ushort4 st;
    st.x = f2b(o[j][0] * inv);
    st.y = f2b(o[j][1] * inv);
    st.z = f2b(o[j][2] * inv);
    st.w = f2b(o[j][3] * inv);
    *(ushort4*)&dst[j * 16 + g4 * 4] = st;
  }
}

// ---------------------------------------------------------------------------
extern "C" void kernel_launch(void* const* d_in, const int* in_sizes, int n_in,
                              void* d_out, int out_size, void* d_ws, size_t ws_size,
                              hipStream_t stream) {
  const float* x  = (const float*)d_in[0];
  const float* Wq = (const float*)d_in[1];
  const float* bq = (const float*)d_in[2];
  const float* Wk = (const float*)d_in[3];
  const float* bk = (const float*)d_in[4];
  const float* Wv = (const float*)d_in[5];
  const float* bv = (const float*)d_in[6];
  const float* Wo = (const float*)d_in[7];
  const float* bo = (const float*)d_in[8];
  const int* mask = (const int*)d_in[9];
  float* out = (float*)d_out;

  // workspace layout (bytes)
  const size_t OFF_XB   = 0;                       // 25165824 : x bf16
  const size_t OFF_WT   = 25165824;                // 4718592  : Wt[4][n][k] bf16
  const size_t OFF_COS  = 29884416;                // 131072
  const size_t OFF_SIN  = 30015488;                // 131072
  const size_t OFF_QKVB = 30146560;                // 75497472 : q,k,v bf16 [3][M][768]
  const size_t OFF_QH   = 105644032;               // 25165824 : Q head layout
  const size_t OFF_KH   = 130809856;               // 25165824
  const size_t OFF_VT   = 155975680;               // 25165824 : V^T head layout
  const size_t REQUIRED = 181141504;
  if (ws_size < REQUIRED) return;  // ws too small — fail loudly (poisoned out)

  char* w = (char*)d_ws;
  unsigned short* xb   = (unsigned short*)(w + OFF_XB);
  unsigned short* Wt   = (unsigned short*)(w + OFF_WT);
  float* cosT          = (float*)(w + OFF_COS);
  float* sinT          = (float*)(w + OFF_SIN);
  unsigned short* qkvb = (unsigned short*)(w + OFF_QKVB);
  unsigned short* Qh   = (unsigned short*)(w + OFF_QH);
  unsigned short* Kh   = (unsigned short*)(w + OFF_KH);
  unsigned short* Vt   = (unsigned short*)(w + OFF_VT);
  unsigned short* attnb = qkvb;  // alias: qkvb dead after rope_pack/v_pack

  cvt_x<<<2048, 256, 0, stream>>>(x, xb);
  prep_w<<<dim3(12, 12, 4), 256, 0, stream>>>(Wq, Wk, Wv, Wo, Wt);
  rope_tab<<<128, 256, 0, stream>>>(cosT, sinT);
  gemm_qkv<<<dim3(128, 6, 3), 256, 0, stream>>>(xb, Wt, bq, bk, bv, qkvb);
  rope_pack<<<dim3(768, 1, 2), 256, 0, stream>>>(qkvb, cosT, sinT, Qh, Kh);
  v_pack<<<dim3(16, 192), 256, 0, stream>>>(qkvb + (size_t)2 * M_TOT * DM, Vt);
  attn_fwd<<<dim3(16, 192), 256, 0, stream>>>(Qh, Kh, Vt, mask, attnb);
  gemm_o<<<dim3(128, 6), 256, 0, stream>>>(attnb, Wt + (size_t)3 * DM * DM, bo, out);
}